// Round 1
// baseline (444.974 us; speedup 1.0000x reference)
//
#include <hip/hip_runtime.h>

namespace {

constexpr int U = 128;
constexpr float INV_SQRT3 = 0.57735026918962576f;  // 1/sqrt(3)
constexpr float INV_SQRT2 = 0.70710678118654752f;  // 1/sqrt(2)

// 12-byte, 4-byte-aligned vector (HIP float3 alignment is not guaranteed 4B;
// plain struct keeps reinterpret at 12B strides legal).
struct F3 { float x, y, z; };

__global__ __launch_bounds__(256) void tp_kernel(
    const float* __restrict__ x1, const float* __restrict__ x2,
    const float* __restrict__ w, float* __restrict__ out, int nrows) {
  const int t = blockIdx.x * blockDim.x + threadIdx.x;
  const int b = t >> 7;          // batch row
  const int u = t & (U - 1);     // channel
  if (b >= nrows) return;

  const float* x1row = x1 + (size_t)b * (4 * U);
  // coalesced: lane-stride 4B
  const float s0 = x1row[u];
  // lane-stride 12B, wave covers contiguous 768B window
  const F3 s1 = reinterpret_cast<const F3*>(x1row + U)[u];
  // 16B broadcast per row (all 128 lanes of the row read the same float4)
  const float4 y = reinterpret_cast<const float4*>(x2)[b];  // y.x=y0, (y.y,y.z,y.w)=y1

  // weights: 5 coalesced dword loads, L2-resident after first touch
  const float w0 = w[u];
  const float w1 = w[U + u];
  const float w2 = w[2 * U + u];
  const float w3 = w[3 * U + u];
  const float w4 = w[4 * U + u];

  float* orow = out + (size_t)b * (11 * U);

  // o0[u] = w0 * s0 * y0
  orow[u] = w0 * s0 * y.x;

  // o1[u,i] = w1 * s0 * y1[i]
  const float t1 = w1 * s0;
  reinterpret_cast<F3*>(orow + U)[u] = {t1 * y.y, t1 * y.z, t1 * y.w};

  // o2[u,i] = w2 * s1[i] * y0
  const float t2 = w2 * y.x;
  reinterpret_cast<F3*>(orow + 4 * U)[u] = {t2 * s1.x, t2 * s1.y, t2 * s1.z};

  // o3[u] = w3 * dot(s1, y1) / sqrt(3)
  orow[7 * U + u] =
      w3 * (s1.x * y.y + s1.y * y.z + s1.z * y.w) * INV_SQRT3;

  // o4[u,k] = w4 * cross(s1, y1)[k] / sqrt(2)
  const float c0 = s1.y * y.w - s1.z * y.z;
  const float c1 = s1.z * y.y - s1.x * y.w;
  const float c2 = s1.x * y.z - s1.y * y.y;
  const float t4 = w4 * INV_SQRT2;
  reinterpret_cast<F3*>(orow + 8 * U)[u] = {t4 * c0, t4 * c1, t4 * c2};
}

}  // namespace

extern "C" void kernel_launch(void* const* d_in, const int* in_sizes, int n_in,
                              void* d_out, int out_size, void* d_ws, size_t ws_size,
                              hipStream_t stream) {
  const float* x1 = (const float*)d_in[0];
  const float* x2 = (const float*)d_in[1];
  const float* w  = (const float*)d_in[2];
  float* out = (float*)d_out;

  const int nrows = in_sizes[0] / (4 * U);   // B
  const int total = nrows * U;               // one thread per (b,u)
  const int block = 256;
  const int grid = (total + block - 1) / block;

  hipLaunchKernelGGL(tp_kernel, dim3(grid), dim3(block), 0, stream,
                     x1, x2, w, out, nrows);
}